// Round 12
// baseline (119.892 us; speedup 1.0000x reference)
//
#include <hip/hip_runtime.h>
#include <math.h>

#define HDIM 128
#define WDIM 128
#define CDIM 64
#define BDIM 4

#define TILE_W 16
#define TILE_H 4
#define HALO_W 20
#define HALO_H 8
#define NHALO (HALO_W * HALO_H)   // 160 halo px = 10 M-tiles of 16
#define PSTRIDE 68                // cms/crs pixel stride (16B-aligned, 4 mod 32)

typedef short bf16x8 __attribute__((ext_vector_type(8)));
typedef float f32x4  __attribute__((ext_vector_type(4)));

// exact fp32 -> bf16 hi/lo split (3-product emulation, |err| ~ 2^-14)
__device__ __forceinline__ void split_bf16(float f, short& hi, short& lo) {
    unsigned u = __float_as_uint(f);
    hi = (short)(u >> 16);
    float hf = __uint_as_float(u & 0xffff0000u);
    float l  = f - hf;
    lo = (short)(__float_as_uint(l) >> 16);
}

__device__ __forceinline__ void build_A(const float4 p0, const float4 p1,
                                        const float4 p2, const float4 p3,
                                        bf16x8 Ahi[2], bf16x8 Alo[2]) {
    float fv[16] = {p0.x,p0.y,p0.z,p0.w, p1.x,p1.y,p1.z,p1.w,
                    p2.x,p2.y,p2.z,p2.w, p3.x,p3.y,p3.z,p3.w};
    #pragma unroll
    for (int ks = 0; ks < 2; ++ks)
        #pragma unroll
        for (int j = 0; j < 8; ++j) {
            short hi, lo; split_bf16(fv[8 * ks + j], hi, lo);
            Ahi[ks][j] = hi; Alo[ks][j] = lo;
        }
}

// ---------------------------------------------------------------------------
// Fused MFMA local-attn, round-12: OCCUPANCY round.
//   r9-r11 post-mortem: three structurally different kernels (5-barrier LDS-W,
//   hoisted prefetch, 2-barrier global-W) all ~91 us total — instruction mix
//   and barrier count are NOT the bottleneck. Invariant was 2 blocks/CU
//   (65,280 B LDS) = 8 waves/CU, one block generation, and ~8 us/CU of
//   serialized scores-phase LDS reads. This round: TILE 16x4 (64 px, 4
//   threads/px), halo 20x8=160 px, crs 43,520 B -> 3 blocks/CU (12 waves),
//   grid 1024. Wave-local cm->qv preserved (wave wv computes px 16wv..+15 =
//   its own quarter-threads' pixels). Scores 4-way channel split, combined
//   via shfl_xor(1)+shfl_xor(2); writes split 7/6/7/6 (compile-time idx).
//   __launch_bounds__(256,3) caps VGPR at 170 (est. ~165).
// ---------------------------------------------------------------------------
__global__ __launch_bounds__(256, 3)
void fused_mfma_local_attn(const float* __restrict__ xm,
                           const float* __restrict__ xr,
                           const float* __restrict__ Wm,
                           const float* __restrict__ Wr,
                           float* __restrict__ out) {
    __shared__ float lds[NHALO * PSTRIDE];   // 43,520 B
    float* cms = lds;                        // [64][68]  (phase 2-3)
    float* crs = lds;                        // [160][68] (phase 4+)

    const int t    = threadIdx.x;
    const int lane = t & 63;
    const int wv   = t >> 6;
    const int m    = lane & 15;
    const int quad = lane >> 4;
    const int tx0  = blockIdx.x * TILE_W;
    const int ty0  = blockIdx.y * TILE_H;
    const int b    = blockIdx.z;

    // ============ prefetch A-side payloads ============
    float4 am[4];                       // xm: 1 M-tile per wave (row wv)
    {
        const float* ap = xm + (((size_t)b * HDIM + ty0 + wv) * WDIM
                                + tx0 + m) * CDIM + quad * 8;
        am[0] = *(const float4*)(ap);
        am[1] = *(const float4*)(ap + 4);
        am[2] = *(const float4*)(ap + 32);
        am[3] = *(const float4*)(ap + 36);
    }

    float4 ar[2][4];                    // xr halo: tiles tj = wv, wv+4
    #pragma unroll
    for (int s = 0; s < 2; ++s) {
        const int tj = wv + 4 * s;
        const int hp = tj * 16 + m;
        const int hy = hp / HALO_W;
        const int hx = hp - hy * HALO_W;
        const int gy = ty0 + hy - 2, gx = tx0 + hx - 2;
        float4 z = make_float4(0.f, 0.f, 0.f, 0.f);
        ar[s][0] = z; ar[s][1] = z; ar[s][2] = z; ar[s][3] = z;
        if (gy >= 0 && gy < HDIM && gx >= 0 && gx < WDIM) {
            const float* ap = xr + (((size_t)b * HDIM + gy) * WDIM + gx) * CDIM
                              + quad * 8;
            ar[s][0] = *(const float4*)(ap);
            ar[s][1] = *(const float4*)(ap + 4);
            ar[s][2] = *(const float4*)(ap + 32);
            ar[s][3] = *(const float4*)(ap + 36);
        }
    }

    // ============ Bm frags from GLOBAL Wm ============
    bf16x8 Bhi[2][4], Blo[2][4];
    #pragma unroll
    for (int ks = 0; ks < 2; ++ks)
        #pragma unroll
        for (int nt = 0; nt < 4; ++nt)
            #pragma unroll
            for (int j = 0; j < 8; ++j) {
                float f = Wm[(ks * 32 + quad * 8 + j) * CDIM + nt * 16 + m];
                short hi, lo; split_bf16(f, hi, lo);
                Bhi[ks][nt][j] = hi; Blo[ks][nt][j] = lo;
            }

    // ============ cm GEMM (1 M-tile/wave) -> wave-private cms slice ========
    {
        bf16x8 Ahi[2], Alo[2];
        build_A(am[0], am[1], am[2], am[3], Ahi, Alo);
        f32x4 acc[4];
        #pragma unroll
        for (int nt = 0; nt < 4; ++nt)
            { acc[nt][0]=0.f; acc[nt][1]=0.f; acc[nt][2]=0.f; acc[nt][3]=0.f; }
        #pragma unroll
        for (int ks = 0; ks < 2; ++ks)
            #pragma unroll
            for (int nt = 0; nt < 4; ++nt) {
                acc[nt] = __builtin_amdgcn_mfma_f32_16x16x32_bf16(Ahi[ks], Bhi[ks][nt], acc[nt], 0,0,0);
                acc[nt] = __builtin_amdgcn_mfma_f32_16x16x32_bf16(Ahi[ks], Blo[ks][nt], acc[nt], 0,0,0);
                acc[nt] = __builtin_amdgcn_mfma_f32_16x16x32_bf16(Alo[ks], Bhi[ks][nt], acc[nt], 0,0,0);
            }
        #pragma unroll
        for (int nt = 0; nt < 4; ++nt)
            #pragma unroll
            for (int r = 0; r < 4; ++r)
                cms[(wv * 16 + quad * 4 + r) * PSTRIDE + nt * 16 + m] = acc[nt][r];
    }

    // ============ qv extract — WAVE-LOCAL, no barrier ============
    const int pl = t >> 2;              // 16wv..16wv+15: rows this wave wrote
    const int cq = t & 3;               // channel quarter
    float4 qv[4];
    #pragma unroll
    for (int mq = 0; mq < 4; ++mq)
        qv[mq] = *(const float4*)&cms[pl * PSTRIDE + cq * 16 + 4 * mq];

    // ============ issue xr tile 2 loads (tj = wv+8, valid wv<2) ============
    float4 ar2[4];
    {
        const int tj = wv + 8;
        float4 z = make_float4(0.f, 0.f, 0.f, 0.f);
        ar2[0] = z; ar2[1] = z; ar2[2] = z; ar2[3] = z;
        if (tj < 10) {
            const int hp = tj * 16 + m;
            const int hy = hp / HALO_W;
            const int hx = hp - hy * HALO_W;
            const int gy = ty0 + hy - 2, gx = tx0 + hx - 2;
            if (gy >= 0 && gy < HDIM && gx >= 0 && gx < WDIM) {
                const float* ap = xr + (((size_t)b * HDIM + gy) * WDIM + gx) * CDIM
                                  + quad * 8;
                ar2[0] = *(const float4*)(ap);
                ar2[1] = *(const float4*)(ap + 4);
                ar2[2] = *(const float4*)(ap + 32);
                ar2[3] = *(const float4*)(ap + 36);
            }
        }
    }

    // ============ Br frags from GLOBAL Wr ============
    #pragma unroll
    for (int ks = 0; ks < 2; ++ks)
        #pragma unroll
        for (int nt = 0; nt < 4; ++nt)
            #pragma unroll
            for (int j = 0; j < 8; ++j) {
                float f = Wr[(ks * 32 + quad * 8 + j) * CDIM + nt * 16 + m];
                short hi, lo; split_bf16(f, hi, lo);
                Bhi[ks][nt][j] = hi; Blo[ks][nt][j] = lo;
            }

    __syncthreads();    // A: all qv extracted before crs overwrites cms

    // ============ cr halo GEMM (10 M-tiles over 4 waves) -> crs ============
    #pragma unroll
    for (int s = 0; s < 3; ++s) {
        const int tj = wv + 4 * s;
        if (tj < 10) {
            const float4* pa = (s < 2) ? ar[s] : ar2;
            bf16x8 Ahi[2], Alo[2];
            build_A(pa[0], pa[1], pa[2], pa[3], Ahi, Alo);
            f32x4 acc[4];
            #pragma unroll
            for (int nt = 0; nt < 4; ++nt)
                { acc[nt][0]=0.f; acc[nt][1]=0.f; acc[nt][2]=0.f; acc[nt][3]=0.f; }
            #pragma unroll
            for (int ks = 0; ks < 2; ++ks)
                #pragma unroll
                for (int nt = 0; nt < 4; ++nt) {
                    acc[nt] = __builtin_amdgcn_mfma_f32_16x16x32_bf16(Ahi[ks], Bhi[ks][nt], acc[nt], 0,0,0);
                    acc[nt] = __builtin_amdgcn_mfma_f32_16x16x32_bf16(Ahi[ks], Blo[ks][nt], acc[nt], 0,0,0);
                    acc[nt] = __builtin_amdgcn_mfma_f32_16x16x32_bf16(Alo[ks], Bhi[ks][nt], acc[nt], 0,0,0);
                }
            #pragma unroll
            for (int nt = 0; nt < 4; ++nt)
                #pragma unroll
                for (int r = 0; r < 4; ++r)
                    crs[(tj * 16 + quad * 4 + r) * PSTRIDE + nt * 16 + m] = acc[nt][r];
        }
    }
    __syncthreads();    // B: crs complete

    // ============ scores + softmax (4-way channel split) ============
    const int lx = pl & (TILE_W - 1);
    const int ly = pl >> 4;             // 0..3
    const size_t gpx = ((size_t)b * HDIM + ty0 + ly) * WDIM + tx0 + lx;

    float s[26];
    #pragma unroll
    for (int k = 0; k < 25; ++k) {
        const int i = k / 5, j = k % 5;
        const int p = (ly + i) * HALO_W + (lx + j);
        const float4* kp = (const float4*)&crs[p * PSTRIDE + cq * 16];
        float acc = 0.f;
        #pragma unroll
        for (int mq = 0; mq < 4; ++mq) {
            float4 v = kp[mq];
            acc = fmaf(qv[mq].x, v.x, acc);
            acc = fmaf(qv[mq].y, v.y, acc);
            acc = fmaf(qv[mq].z, v.z, acc);
            acc = fmaf(qv[mq].w, v.w, acc);
        }
        s[k] = acc;
    }
    {
        float acc = 0.f;
        #pragma unroll
        for (int mq = 0; mq < 4; ++mq) {
            float4 v = qv[mq];
            acc = fmaf(v.x, v.x, acc);
            acc = fmaf(v.y, v.y, acc);
            acc = fmaf(v.z, v.z, acc);
            acc = fmaf(v.w, v.w, acc);
        }
        s[25] = acc;
    }

    // combine the four channel quarters (lanes differ in bits 0-1)
    #pragma unroll
    for (int k = 0; k < 26; ++k) s[k] += __shfl_xor(s[k], 1);
    #pragma unroll
    for (int k = 0; k < 26; ++k) s[k] += __shfl_xor(s[k], 2);

    float mx = s[0];
    #pragma unroll
    for (int k = 1; k < 26; ++k) mx = fmaxf(mx, s[k]);
    float sum = 0.f;
    #pragma unroll
    for (int k = 0; k < 26; ++k) { s[k] = __expf(s[k] - mx); sum += s[k]; }
    const float inv = 1.f / sum;

    // writes split 7/6/7/6 across the quarter-threads; compile-time indices
    float* op = &out[gpx * 26];
    if (cq == 0) {
        #pragma unroll
        for (int k = 0; k < 7; ++k) op[k] = s[k] * inv;
    } else if (cq == 1) {
        #pragma unroll
        for (int k = 0; k < 6; ++k) op[7 + k] = s[7 + k] * inv;
    } else if (cq == 2) {
        #pragma unroll
        for (int k = 0; k < 7; ++k) op[13 + k] = s[13 + k] * inv;
    } else {
        #pragma unroll
        for (int k = 0; k < 6; ++k) op[20 + k] = s[20 + k] * inv;
    }
}

// ---------------------------------------------------------------------------
extern "C" void kernel_launch(void* const* d_in, const int* in_sizes, int n_in,
                              void* d_out, int out_size, void* d_ws, size_t ws_size,
                              hipStream_t stream) {
    const float* xm = (const float*)d_in[0];
    const float* xr = (const float*)d_in[1];
    const float* Wm = (const float*)d_in[2];
    const float* Wr = (const float*)d_in[3];
    float* outp = (float*)d_out;

    dim3 g(WDIM / TILE_W, HDIM / TILE_H, BDIM);   // 8 x 32 x 4 = 1024 blocks
    fused_mfma_local_attn<<<g, 256, 0, stream>>>(xm, xr, Wm, Wr, outp);
}

// Round 13
// 94.689 us; speedup vs baseline: 1.2662x; 1.2662x over previous
//
#include <hip/hip_runtime.h>
#include <math.h>

#define HDIM 128
#define WDIM 128
#define CDIM 64
#define BDIM 4

#define TILE_W 8
#define TILE_H 8
#define HALO_W 12
#define HALO_H 12
#define NHALO (HALO_W * HALO_H)   // 144 halo px = 9 M-tiles of 16
#define PSTRIDE 68                // cms/crs pixel stride (16B-aligned, 4 mod 32)

typedef short bf16x8 __attribute__((ext_vector_type(8)));
typedef float f32x4  __attribute__((ext_vector_type(4)));

// exact fp32 -> bf16 hi/lo split (3-product emulation, |err| ~ 2^-14)
__device__ __forceinline__ void split_bf16(float f, short& hi, short& lo) {
    unsigned u = __float_as_uint(f);
    hi = (short)(u >> 16);
    float hf = __uint_as_float(u & 0xffff0000u);
    float l  = f - hf;
    lo = (short)(__float_as_uint(l) >> 16);
}

__device__ __forceinline__ void build_A(const float4 p0, const float4 p1,
                                        const float4 p2, const float4 p3,
                                        bf16x8 Ahi[2], bf16x8 Alo[2]) {
    float fv[16] = {p0.x,p0.y,p0.z,p0.w, p1.x,p1.y,p1.z,p1.w,
                    p2.x,p2.y,p2.z,p2.w, p3.x,p3.y,p3.z,p3.w};
    #pragma unroll
    for (int ks = 0; ks < 2; ++ks)
        #pragma unroll
        for (int j = 0; j < 8; ++j) {
            short hi, lo; split_bf16(fv[8 * ks + j], hi, lo);
            Ahi[ks][j] = hi; Alo[ks][j] = lo;
        }
}

// ---------------------------------------------------------------------------
// Fused MFMA local-attn, round-13: MULTI-GENERATION round.
//   r12 post-mortem: launch_bounds(256,3) capped VGPR at ~170 < ~190 demand
//   -> wholesale spill (VGPR=84, WRITE_SIZE 43.7 MB vs 6.8 expected) -> 120us.
//   r9-r11 invariant: 512 blocks = ONE co-resident generation at 2 blocks/CU;
//   every phase's latency fully exposed. This round: 8x8 tile, 128 threads
//   (2 thr/px — r11's proven no-spill register budget), halo 12x12=144 px,
//   crs 39,168 B -> 4 blocks/CU, grid 1024 = TWO generations so gen-2 compute
//   fills gen-1 stalls. Wave-local cm->qv preserved (wave wv's cm tiles
//   2wv,2wv+1 = px 32wv..32wv+31 = its own threads' pixels). 2 barriers,
//   global-W B-frags, 3-product split-bf16 MFMA. launch_bounds(128,2):
//   VGPR cap 256 — NO spill this time.
// ---------------------------------------------------------------------------
__global__ __launch_bounds__(128, 2)
void fused_mfma_local_attn(const float* __restrict__ xm,
                           const float* __restrict__ xr,
                           const float* __restrict__ Wm,
                           const float* __restrict__ Wr,
                           float* __restrict__ out) {
    __shared__ float lds[NHALO * PSTRIDE];   // 39,168 B
    float* cms = lds;                        // [64][68]  (phase 2-3)
    float* crs = lds;                        // [144][68] (phase 4+)

    const int t    = threadIdx.x;            // 0..127
    const int lane = t & 63;
    const int wv   = t >> 6;                 // wave 0..1
    const int m    = lane & 15;
    const int quad = lane >> 4;
    const int tx0  = blockIdx.x * TILE_W;
    const int ty0  = blockIdx.y * TILE_H;
    const int b    = blockIdx.z;

    // ============ prefetch A-side payloads (one overlapped episode) ========
    float4 am[2][4];                    // xm: M-tiles 2wv, 2wv+1
    #pragma unroll
    for (int s = 0; s < 2; ++s) {
        const int px = (2 * wv + s) * 16 + m;          // block-local pixel
        const float* ap = xm + (((size_t)b * HDIM + ty0 + (px >> 3)) * WDIM
                                + tx0 + (px & 7)) * CDIM + quad * 8;
        am[s][0] = *(const float4*)(ap);
        am[s][1] = *(const float4*)(ap + 4);
        am[s][2] = *(const float4*)(ap + 32);
        am[s][3] = *(const float4*)(ap + 36);
    }

    float4 ar[2][4];                    // xr halo: tiles tj = wv, wv+2
    #pragma unroll
    for (int s = 0; s < 2; ++s) {
        const int tj = wv + 2 * s;
        const int hp = tj * 16 + m;
        const int hy = hp / HALO_W;
        const int hx = hp - hy * HALO_W;
        const int gy = ty0 + hy - 2, gx = tx0 + hx - 2;
        float4 z = make_float4(0.f, 0.f, 0.f, 0.f);
        ar[s][0] = z; ar[s][1] = z; ar[s][2] = z; ar[s][3] = z;
        if (gy >= 0 && gy < HDIM && gx >= 0 && gx < WDIM) {
            const float* ap = xr + (((size_t)b * HDIM + gy) * WDIM + gx) * CDIM
                              + quad * 8;
            ar[s][0] = *(const float4*)(ap);
            ar[s][1] = *(const float4*)(ap + 4);
            ar[s][2] = *(const float4*)(ap + 32);
            ar[s][3] = *(const float4*)(ap + 36);
        }
    }

    // ============ Bm frags from GLOBAL Wm (L2-resident) ============
    bf16x8 Bhi[2][4], Blo[2][4];
    #pragma unroll
    for (int ks = 0; ks < 2; ++ks)
        #pragma unroll
        for (int nt = 0; nt < 4; ++nt)
            #pragma unroll
            for (int j = 0; j < 8; ++j) {
                float f = Wm[(ks * 32 + quad * 8 + j) * CDIM + nt * 16 + m];
                short hi, lo; split_bf16(f, hi, lo);
                Bhi[ks][nt][j] = hi; Blo[ks][nt][j] = lo;
            }

    // ============ cm GEMM (2 M-tiles/wave) -> wave-private cms slice =======
    #pragma unroll
    for (int s = 0; s < 2; ++s) {
        const int tile = 2 * wv + s;
        bf16x8 Ahi[2], Alo[2];
        build_A(am[s][0], am[s][1], am[s][2], am[s][3], Ahi, Alo);
        f32x4 acc[4];
        #pragma unroll
        for (int nt = 0; nt < 4; ++nt)
            { acc[nt][0]=0.f; acc[nt][1]=0.f; acc[nt][2]=0.f; acc[nt][3]=0.f; }
        #pragma unroll
        for (int ks = 0; ks < 2; ++ks)
            #pragma unroll
            for (int nt = 0; nt < 4; ++nt) {
                acc[nt] = __builtin_amdgcn_mfma_f32_16x16x32_bf16(Ahi[ks], Bhi[ks][nt], acc[nt], 0,0,0);
                acc[nt] = __builtin_amdgcn_mfma_f32_16x16x32_bf16(Ahi[ks], Blo[ks][nt], acc[nt], 0,0,0);
                acc[nt] = __builtin_amdgcn_mfma_f32_16x16x32_bf16(Alo[ks], Bhi[ks][nt], acc[nt], 0,0,0);
            }
        #pragma unroll
        for (int nt = 0; nt < 4; ++nt)
            #pragma unroll
            for (int r = 0; r < 4; ++r)
                cms[(tile * 16 + quad * 4 + r) * PSTRIDE + nt * 16 + m] = acc[nt][r];
    }

    // ============ qv extract — WAVE-LOCAL, no barrier ============
    const int pl = t >> 1;              // 32wv..32wv+31: rows this wave wrote
    const int cg = t & 1;
    float4 qv[8];
    #pragma unroll
    for (int mq = 0; mq < 8; ++mq)
        qv[mq] = *(const float4*)&cms[pl * PSTRIDE + cg * 32 + 4 * mq];

    // ============ issue xr tiles 2-4 loads (tj = wv+4, wv+6, wv+8) =========
    float4 ar2[3][4];
    #pragma unroll
    for (int s = 0; s < 3; ++s) {
        const int tj = wv + 2 * (s + 2);
        float4 z = make_float4(0.f, 0.f, 0.f, 0.f);
        ar2[s][0] = z; ar2[s][1] = z; ar2[s][2] = z; ar2[s][3] = z;
        if (tj < 9) {
            const int hp = tj * 16 + m;
            const int hy = hp / HALO_W;
            const int hx = hp - hy * HALO_W;
            const int gy = ty0 + hy - 2, gx = tx0 + hx - 2;
            if (gy >= 0 && gy < HDIM && gx >= 0 && gx < WDIM) {
                const float* ap = xr + (((size_t)b * HDIM + gy) * WDIM + gx) * CDIM
                                  + quad * 8;
                ar2[s][0] = *(const float4*)(ap);
                ar2[s][1] = *(const float4*)(ap + 4);
                ar2[s][2] = *(const float4*)(ap + 32);
                ar2[s][3] = *(const float4*)(ap + 36);
            }
        }
    }

    // ============ Br frags from GLOBAL Wr ============
    #pragma unroll
    for (int ks = 0; ks < 2; ++ks)
        #pragma unroll
        for (int nt = 0; nt < 4; ++nt)
            #pragma unroll
            for (int j = 0; j < 8; ++j) {
                float f = Wr[(ks * 32 + quad * 8 + j) * CDIM + nt * 16 + m];
                short hi, lo; split_bf16(f, hi, lo);
                Bhi[ks][nt][j] = hi; Blo[ks][nt][j] = lo;
            }

    __syncthreads();    // A: all qv extracted before crs overwrites cms

    // ============ cr halo GEMM (9 M-tiles over 2 waves) -> crs ============
    #pragma unroll
    for (int s = 0; s < 5; ++s) {
        const int tj = wv + 2 * s;
        if (tj < 9) {
            const float4* pa = (s < 2) ? ar[s] : ar2[s - 2];
            bf16x8 Ahi[2], Alo[2];
            build_A(pa[0], pa[1], pa[2], pa[3], Ahi, Alo);
            f32x4 acc[4];
            #pragma unroll
            for (int nt = 0; nt < 4; ++nt)
                { acc[nt][0]=0.f; acc[nt][1]=0.f; acc[nt][2]=0.f; acc[nt][3]=0.f; }
            #pragma unroll
            for (int ks = 0; ks < 2; ++ks)
                #pragma unroll
                for (int nt = 0; nt < 4; ++nt) {
                    acc[nt] = __builtin_amdgcn_mfma_f32_16x16x32_bf16(Ahi[ks], Bhi[ks][nt], acc[nt], 0,0,0);
                    acc[nt] = __builtin_amdgcn_mfma_f32_16x16x32_bf16(Ahi[ks], Blo[ks][nt], acc[nt], 0,0,0);
                    acc[nt] = __builtin_amdgcn_mfma_f32_16x16x32_bf16(Alo[ks], Bhi[ks][nt], acc[nt], 0,0,0);
                }
            #pragma unroll
            for (int nt = 0; nt < 4; ++nt)
                #pragma unroll
                for (int r = 0; r < 4; ++r)
                    crs[(tj * 16 + quad * 4 + r) * PSTRIDE + nt * 16 + m] = acc[nt][r];
        }
    }
    __syncthreads();    // B: crs complete

    // ============ scores + softmax (proven) ============
    const int lx = pl & (TILE_W - 1);
    const int ly = pl >> 3;             // 0..7
    const size_t gpx = ((size_t)b * HDIM + ty0 + ly) * WDIM + tx0 + lx;

    float s[26];
    #pragma unroll
    for (int k = 0; k < 25; ++k) {
        const int i = k / 5, j = k % 5;
        const int p = (ly + i) * HALO_W + (lx + j);
        const float4* kp = (const float4*)&crs[p * PSTRIDE + cg * 32];
        float acc = 0.f;
        #pragma unroll
        for (int mq = 0; mq < 8; ++mq) {
            float4 v = kp[mq];
            acc = fmaf(qv[mq].x, v.x, acc);
            acc = fmaf(qv[mq].y, v.y, acc);
            acc = fmaf(qv[mq].z, v.z, acc);
            acc = fmaf(qv[mq].w, v.w, acc);
        }
        s[k] = acc;
    }
    {
        float acc = 0.f;
        #pragma unroll
        for (int mq = 0; mq < 8; ++mq) {
            float4 v = qv[mq];
            acc = fmaf(v.x, v.x, acc);
            acc = fmaf(v.y, v.y, acc);
            acc = fmaf(v.z, v.z, acc);
            acc = fmaf(v.w, v.w, acc);
        }
        s[25] = acc;
    }

    #pragma unroll
    for (int k = 0; k < 26; ++k) s[k] += __shfl_xor(s[k], 1);

    float mx = s[0];
    #pragma unroll
    for (int k = 1; k < 26; ++k) mx = fmaxf(mx, s[k]);
    float sum = 0.f;
    #pragma unroll
    for (int k = 0; k < 26; ++k) { s[k] = __expf(s[k] - mx); sum += s[k]; }
    const float inv = 1.f / sum;

    float* op = &out[gpx * 26 + cg * 13];
    if (cg == 0) {
        #pragma unroll
        for (int k = 0; k < 13; ++k) op[k] = s[k] * inv;
    } else {
        #pragma unroll
        for (int k = 0; k < 13; ++k) op[k] = s[13 + k] * inv;
    }
}

// ---------------------------------------------------------------------------
extern "C" void kernel_launch(void* const* d_in, const int* in_sizes, int n_in,
                              void* d_out, int out_size, void* d_ws, size_t ws_size,
                              hipStream_t stream) {
    const float* xm = (const float*)d_in[0];
    const float* xr = (const float*)d_in[1];
    const float* Wm = (const float*)d_in[2];
    const float* Wr = (const float*)d_in[3];
    float* outp = (float*)d_out;

    dim3 g(WDIM / TILE_W, HDIM / TILE_H, BDIM);   // 16 x 16 x 4 = 1024 blocks
    fused_mfma_local_attn<<<g, 128, 0, stream>>>(xm, xr, Wm, Wr, outp);
}

// Round 14
// 89.746 us; speedup vs baseline: 1.3359x; 1.0551x over previous
//
#include <hip/hip_runtime.h>
#include <math.h>

#define HDIM 128
#define WDIM 128
#define CDIM 64
#define BDIM 4

#define TILE_W 16
#define TILE_H 8
#define HALO_W 20
#define HALO_H 12
#define NHALO (HALO_W * HALO_H)   // 240 halo px = 15 M-tiles of 16
#define PSTRIDE 68                // cm/crs pixel stride (16B-aligned, 4 mod 32)
#define WSTRIDE 65                // W LDS stride (2-way banks on frag reads)

typedef short bf16x8 __attribute__((ext_vector_type(8)));
typedef float f32x4  __attribute__((ext_vector_type(4)));

// exact fp32 -> bf16 hi/lo split (3-product emulation, |err| ~ 2^-14)
__device__ __forceinline__ void split_bf16(float f, short& hi, short& lo) {
    unsigned u = __float_as_uint(f);
    hi = (short)(u >> 16);
    float hf = __uint_as_float(u & 0xffff0000u);
    float l  = f - hf;
    lo = (short)(__float_as_uint(l) >> 16);
}

// ---------------------------------------------------------------------------
// Fused MFMA local-attn — RESTORED round-9 kernel (measured best: 90.0 us).
//   Exploration ledger (r10-r13): hoisted prefetch 91.0; 2-barrier/global-W
//   91.8; 16x4 VGPR-capped spill 119.9; 8x8 4-blk/CU 2-gen 94.7. Five
//   structural axes all within noise of r9 -> kernel is at a ~34 us latency
//   floor (HBM floor ~7 us, scores-LDS ~8 us, all pipes <20% busy at the
//   2-blk/CU occupancy the 65,280 B LDS permits); fixed harness work
//   (268 MB ws 0xAA fill + input restores + out poison) ~56 us dominates.
//   Structure: per 16x8 tile — stage Wm->LDS, Bm frags; cm GEMM (split-bf16
//   3-product MFMA, A-frags direct from global); cm->LDS, qv extract;
//   restage Wr, Br frags; cr halo GEMM (240 px, 15 M-tiles); scores+softmax.
//   LDS multiplex: Wsh[0..4160) | cms[4352..13056) | crs[0..16320).
// ---------------------------------------------------------------------------
__global__ __launch_bounds__(256, 1)
void fused_mfma_local_attn(const float* __restrict__ xm,
                           const float* __restrict__ xr,
                           const float* __restrict__ Wm,
                           const float* __restrict__ Wr,
                           float* __restrict__ out) {
    __shared__ float lds[16320];        // 65,280 B
    float* Wsh = lds;                   // [64][65]
    float* cms = lds + 4352;            // [128][68]
    float* crs = lds;                   // [240][68]

    const int t    = threadIdx.x;
    const int lane = t & 63;
    const int wv   = t >> 6;
    const int m    = lane & 15;
    const int quad = lane >> 4;
    const int tx0  = blockIdx.x * TILE_W;
    const int ty0  = blockIdx.y * TILE_H;
    const int b    = blockIdx.z;

    // ============ phase 1: stage Wm (scalar, stride 65) ============
    #pragma unroll
    for (int i = 0; i < 16; ++i) {
        int L = t + 256 * i;            // wave-aligned: k = L>>6 uniform/wave
        Wsh[(L >> 6) * WSTRIDE + (L & 63)] = Wm[L];
    }
    __syncthreads();

    // build Bm frags: B[k=ks*32+quad*8+j][n=nt*16+m]
    bf16x8 Bhi[2][4], Blo[2][4];
    #pragma unroll
    for (int ks = 0; ks < 2; ++ks)
        #pragma unroll
        for (int nt = 0; nt < 4; ++nt)
            #pragma unroll
            for (int j = 0; j < 8; ++j) {
                float f = Wsh[(ks * 32 + quad * 8 + j) * WSTRIDE + nt * 16 + m];
                short hi, lo; split_bf16(f, hi, lo);
                Bhi[ks][nt][j] = hi; Blo[ks][nt][j] = lo;
            }

    // ============ phase 2: cm GEMM — 2 M-tiles (rows) per wave ============
    #pragma unroll
    for (int s = 0; s < 2; ++s) {
        const int tile = 2 * wv + s;                 // row ty0+tile
        const float* ap = xm + (((size_t)b * HDIM + ty0 + tile) * WDIM
                                + tx0 + m) * CDIM + quad * 8;
        float4 p0 = *(const float4*)(ap);
        float4 p1 = *(const float4*)(ap + 4);
        float4 p2 = *(const float4*)(ap + 32);
        float4 p3 = *(const float4*)(ap + 36);

        bf16x8 Ahi[2], Alo[2];
        {
            float fv[16] = {p0.x,p0.y,p0.z,p0.w, p1.x,p1.y,p1.z,p1.w,
                            p2.x,p2.y,p2.z,p2.w, p3.x,p3.y,p3.z,p3.w};
            #pragma unroll
            for (int ks = 0; ks < 2; ++ks)
                #pragma unroll
                for (int j = 0; j < 8; ++j) {
                    short hi, lo; split_bf16(fv[8 * ks + j], hi, lo);
                    Ahi[ks][j] = hi; Alo[ks][j] = lo;
                }
        }
        f32x4 acc[4];
        #pragma unroll
        for (int nt = 0; nt < 4; ++nt)
            { acc[nt][0]=0.f; acc[nt][1]=0.f; acc[nt][2]=0.f; acc[nt][3]=0.f; }
        #pragma unroll
        for (int ks = 0; ks < 2; ++ks)
            #pragma unroll
            for (int nt = 0; nt < 4; ++nt) {
                acc[nt] = __builtin_amdgcn_mfma_f32_16x16x32_bf16(Ahi[ks], Bhi[ks][nt], acc[nt], 0,0,0);
                acc[nt] = __builtin_amdgcn_mfma_f32_16x16x32_bf16(Ahi[ks], Blo[ks][nt], acc[nt], 0,0,0);
                acc[nt] = __builtin_amdgcn_mfma_f32_16x16x32_bf16(Alo[ks], Bhi[ks][nt], acc[nt], 0,0,0);
            }
        // D: pixel-in-tile = quad*4+r, channel = nt*16+m
        #pragma unroll
        for (int nt = 0; nt < 4; ++nt)
            #pragma unroll
            for (int r = 0; r < 4; ++r)
                cms[(tile * 16 + quad * 4 + r) * PSTRIDE + nt * 16 + m] = acc[nt][r];
    }
    __syncthreads();   // B2: Wsh(Wm) reads + cms writes done

    // ============ phase 3: stage Wr, build Br, extract qv ============
    #pragma unroll
    for (int i = 0; i < 16; ++i) {
        int L = t + 256 * i;
        Wsh[(L >> 6) * WSTRIDE + (L & 63)] = Wr[L];
    }
    __syncthreads();                    // B3

    #pragma unroll
    for (int ks = 0; ks < 2; ++ks)
        #pragma unroll
        for (int nt = 0; nt < 4; ++nt)
            #pragma unroll
            for (int j = 0; j < 8; ++j) {
                float f = Wsh[(ks * 32 + quad * 8 + j) * WSTRIDE + nt * 16 + m];
                short hi, lo; split_bf16(f, hi, lo);
                Bhi[ks][nt][j] = hi; Blo[ks][nt][j] = lo;
            }

    const int pl = t >> 1;
    const int cg = t & 1;
    float4 qv[8];
    #pragma unroll
    for (int mq = 0; mq < 8; ++mq)
        qv[mq] = *(const float4*)&cms[pl * PSTRIDE + cg * 32 + 4 * mq];
    __syncthreads();                    // B4: Wsh/cms reads done before crs

    // ============ phase 4: cr halo GEMM (15 M-tiles over 4 waves) ============
    #pragma unroll
    for (int s = 0; s < 4; ++s) {
        const int tj = wv + 4 * s;
        if (tj < 15) {
            const int hp = tj * 16 + m;
            const int hy = hp / HALO_W;
            const int hx = hp - hy * HALO_W;
            const int gy = ty0 + hy - 2, gx = tx0 + hx - 2;
            float4 p0 = make_float4(0,0,0,0), p1 = p0, p2 = p0, p3 = p0;
            if (gy >= 0 && gy < HDIM && gx >= 0 && gx < WDIM) {
                const float* ap = xr + (((size_t)b * HDIM + gy) * WDIM + gx) * CDIM
                                  + quad * 8;
                p0 = *(const float4*)(ap);
                p1 = *(const float4*)(ap + 4);
                p2 = *(const float4*)(ap + 32);
                p3 = *(const float4*)(ap + 36);
            }
            bf16x8 Ahi[2], Alo[2];
            {
                float fv[16] = {p0.x,p0.y,p0.z,p0.w, p1.x,p1.y,p1.z,p1.w,
                                p2.x,p2.y,p2.z,p2.w, p3.x,p3.y,p3.z,p3.w};
                #pragma unroll
                for (int ks = 0; ks < 2; ++ks)
                    #pragma unroll
                    for (int j = 0; j < 8; ++j) {
                        short hi, lo; split_bf16(fv[8 * ks + j], hi, lo);
                        Ahi[ks][j] = hi; Alo[ks][j] = lo;
                    }
            }
            f32x4 acc[4];
            #pragma unroll
            for (int nt = 0; nt < 4; ++nt)
                { acc[nt][0]=0.f; acc[nt][1]=0.f; acc[nt][2]=0.f; acc[nt][3]=0.f; }
            #pragma unroll
            for (int ks = 0; ks < 2; ++ks)
                #pragma unroll
                for (int nt = 0; nt < 4; ++nt) {
                    acc[nt] = __builtin_amdgcn_mfma_f32_16x16x32_bf16(Ahi[ks], Bhi[ks][nt], acc[nt], 0,0,0);
                    acc[nt] = __builtin_amdgcn_mfma_f32_16x16x32_bf16(Ahi[ks], Blo[ks][nt], acc[nt], 0,0,0);
                    acc[nt] = __builtin_amdgcn_mfma_f32_16x16x32_bf16(Alo[ks], Bhi[ks][nt], acc[nt], 0,0,0);
                }
            #pragma unroll
            for (int nt = 0; nt < 4; ++nt)
                #pragma unroll
                for (int r = 0; r < 4; ++r)
                    crs[(tj * 16 + quad * 4 + r) * PSTRIDE + nt * 16 + m] = acc[nt][r];
        }
    }
    __syncthreads();                    // B5

    // ============ phase 5: scores + softmax (proven) ============
    const int lx = pl & (TILE_W - 1);
    const int ly = pl >> 4;
    const size_t gpx = ((size_t)b * HDIM + ty0 + ly) * WDIM + tx0 + lx;

    float s[26];
    #pragma unroll
    for (int k = 0; k < 25; ++k) {
        const int i = k / 5, j = k % 5;
        const int p = (ly + i) * HALO_W + (lx + j);
        const float4* kp = (const float4*)&crs[p * PSTRIDE + cg * 32];
        float acc = 0.f;
        #pragma unroll
        for (int mq = 0; mq < 8; ++mq) {
            float4 v = kp[mq];
            acc = fmaf(qv[mq].x, v.x, acc);
            acc = fmaf(qv[mq].y, v.y, acc);
            acc = fmaf(qv[mq].z, v.z, acc);
            acc = fmaf(qv[mq].w, v.w, acc);
        }
        s[k] = acc;
    }
    {
        float acc = 0.f;
        #pragma unroll
        for (int mq = 0; mq < 8; ++mq) {
            float4 v = qv[mq];
            acc = fmaf(v.x, v.x, acc);
            acc = fmaf(v.y, v.y, acc);
            acc = fmaf(v.z, v.z, acc);
            acc = fmaf(v.w, v.w, acc);
        }
        s[25] = acc;
    }

    #pragma unroll
    for (int k = 0; k < 26; ++k) s[k] += __shfl_xor(s[k], 1);

    float mx = s[0];
    #pragma unroll
    for (int k = 1; k < 26; ++k) mx = fmaxf(mx, s[k]);
    float sum = 0.f;
    #pragma unroll
    for (int k = 0; k < 26; ++k) { s[k] = __expf(s[k] - mx); sum += s[k]; }
    const float inv = 1.f / sum;

    float* op = &out[gpx * 26 + cg * 13];
    if (cg == 0) {
        #pragma unroll
        for (int k = 0; k < 13; ++k) op[k] = s[k] * inv;
    } else {
        #pragma unroll
        for (int k = 0; k < 13; ++k) op[k] = s[13 + k] * inv;
    }
}

// ---------------------------------------------------------------------------
extern "C" void kernel_launch(void* const* d_in, const int* in_sizes, int n_in,
                              void* d_out, int out_size, void* d_ws, size_t ws_size,
                              hipStream_t stream) {
    const float* xm = (const float*)d_in[0];
    const float* xr = (const float*)d_in[1];
    const float* Wm = (const float*)d_in[2];
    const float* Wr = (const float*)d_in[3];
    float* outp = (float*)d_out;

    dim3 g(WDIM / TILE_W, HDIM / TILE_H, BDIM);   // 8 x 16 x 4 = 512 blocks
    fused_mfma_local_attn<<<g, 256, 0, stream>>>(xm, xr, Wm, Wr, outp);
}